// Round 1
// baseline (425.195 us; speedup 1.0000x reference)
//
#include <hip/hip_runtime.h>
#include <math.h>

#define B_ 4096
#define T_ 64
#define DIN_ 300
#define H_ 3

// Normalize lengths to int32 in ws, auto-detecting int32 vs int64 source
// layout. Valid lengths are in [1,64]; if the raw buffer is int64, every
// odd 32-bit word (high half) is 0; if int32, odd words are lengths >= 1.
// Unambiguous. Only reads first B words of the buffer (safe both ways).
__global__ void prep_lengths_kernel(const int* __restrict__ lraw,
                                    int* __restrict__ len32, int B) {
  __shared__ int flag;
  if (threadIdx.x == 0) flag = 0;
  __syncthreads();
  int local = 0;
  int half = B >> 1;
  for (int i = threadIdx.x; i < half; i += blockDim.x)
    if (lraw[2 * i + 1] != 0) local = 1;
  if (local) atomicOr(&flag, 1);
  __syncthreads();
  int is32 = flag;
  for (int i = threadIdx.x; i < B; i += blockDim.x) {
    int v = is32 ? lraw[i] : lraw[2 * i];
    if (v < 1) v = 1;
    if (v > T_) v = T_;
    len32[i] = v;
  }
}

// One block per batch sample. 4 waves; wave w computes the W_ih projection
// for timesteps t = w, w+4, ... (< L only — skips the masked tail, which is
// the big memory saving). Then thread 0 runs the 3-wide recurrence.
__global__ __launch_bounds__(256) void rnn_fwd_kernel(
    const float* __restrict__ x,      // [B,T,DIN]
    const int* __restrict__ len,      // [B] normalized int32
    const float* __restrict__ W_ih,   // [H,DIN]
    const float* __restrict__ W_hh,   // [H,H]
    const float* __restrict__ b_ih,   // [H]
    const float* __restrict__ b_hh,   // [H]
    float* __restrict__ out) {        // [B,H]
  const int b = blockIdx.x;
  const int tid = threadIdx.x;
  const int wave = tid >> 6;
  const int lane = tid & 63;
  const int L = len[b];

  __shared__ float xb_s[T_][4];  // [t][h] (+pad)

  // Per-lane W_ih fragments. Row = 300 floats = 75 float4 (16B-aligned:
  // row stride 1200 B). Lane l covers float4 #l; lanes <11 also #64+l.
  const float4* W4 = reinterpret_cast<const float4*>(W_ih);
  float4 w0[H_], w1[H_];
#pragma unroll
  for (int h = 0; h < H_; ++h) {
    w0[h] = W4[h * 75 + lane];
    if (lane < 11)
      w1[h] = W4[h * 75 + 64 + lane];
    else
      w1[h] = make_float4(0.f, 0.f, 0.f, 0.f);
  }

  const float* xrow = x + (size_t)b * T_ * DIN_;
  for (int t = wave; t < L; t += 4) {
    const float4* xt4 = reinterpret_cast<const float4*>(xrow + t * DIN_);
    float4 v0 = xt4[lane];
    float4 v1 = make_float4(0.f, 0.f, 0.f, 0.f);
    if (lane < 11) v1 = xt4[64 + lane];  // guard: no OOB past row end
    float acc[H_];
#pragma unroll
    for (int h = 0; h < H_; ++h) {
      acc[h] = v0.x * w0[h].x + v0.y * w0[h].y + v0.z * w0[h].z +
               v0.w * w0[h].w + v1.x * w1[h].x + v1.y * w1[h].y +
               v1.z * w1[h].z + v1.w * w1[h].w;
    }
    // 64-lane tree reduction
#pragma unroll
    for (int off = 32; off > 0; off >>= 1) {
#pragma unroll
      for (int h = 0; h < H_; ++h) acc[h] += __shfl_down(acc[h], off, 64);
    }
    if (lane == 0) {
      xb_s[t][0] = acc[0];
      xb_s[t][1] = acc[1];
      xb_s[t][2] = acc[2];
    }
  }
  __syncthreads();

  if (tid == 0) {
    const float w00 = W_hh[0], w01 = W_hh[1], w02 = W_hh[2];
    const float w10 = W_hh[3], w11 = W_hh[4], w12 = W_hh[5];
    const float w20 = W_hh[6], w21 = W_hh[7], w22 = W_hh[8];
    const float c0 = b_ih[0] + b_hh[0];
    const float c1 = b_ih[1] + b_hh[1];
    const float c2 = b_ih[2] + b_hh[2];
    float h0 = 0.f, h1 = 0.f, h2 = 0.f;
    for (int t = 0; t < L; ++t) {
      float a0 = xb_s[t][0] + c0 + w00 * h0 + w01 * h1 + w02 * h2;
      float a1 = xb_s[t][1] + c1 + w10 * h0 + w11 * h1 + w12 * h2;
      float a2 = xb_s[t][2] + c2 + w20 * h0 + w21 * h1 + w22 * h2;
      h0 = tanhf(a0);
      h1 = tanhf(a1);
      h2 = tanhf(a2);
    }
    out[b * 3 + 0] = h0;
    out[b * 3 + 1] = h1;
    out[b * 3 + 2] = h2;
  }
}

extern "C" void kernel_launch(void* const* d_in, const int* in_sizes, int n_in,
                              void* d_out, int out_size, void* d_ws,
                              size_t ws_size, hipStream_t stream) {
  const float* x = (const float*)d_in[0];
  const int* lraw = (const int*)d_in[1];
  const float* W_ih = (const float*)d_in[2];
  const float* W_hh = (const float*)d_in[3];
  const float* b_ih = (const float*)d_in[4];
  const float* b_hh = (const float*)d_in[5];
  float* out = (float*)d_out;
  int* len32 = (int*)d_ws;  // 16 KB

  prep_lengths_kernel<<<1, 256, 0, stream>>>(lraw, len32, B_);
  rnn_fwd_kernel<<<B_, 256, 0, stream>>>(x, len32, W_ih, W_hh, b_ih, b_hh,
                                         out);
}